// Round 11
// baseline (288.801 us; speedup 1.0000x reference)
//
#include <hip/hip_runtime.h>

// Problem constants
#define VOCAB 50000
#define EMB   300
#define HID   16
#define OUTD  5
#define BSZ   128
#define SEQ   512
#define NTOK  (BSZ*SEQ)

// ws layout (in floats):
//   [0 .. 19200)     wt     : w_ih re-transposed -> [e][u][g], PRE-SCALED by
//                             -log2e (i,f,o) / +2log2e (g) for exp2-activations
//   [19200 .. 19264) bias_t : (b_ih+b_hh) permuted [u][g], same pre-scale
//   [19264 .. +16M)  pre    : pre-gates [tok][u][4] (scaled i,f,g,o per unit)
//   (+ slack)        pad    : k2 prefetch overrun guard (reads only)
#define WT_OFF   0
#define BIAS_OFF 19200
#define PRE_OFF  19264

#define NLOG2E  (-1.44269504f)   // sigmoid gates: exp2(NLOG2E*x) = e^-x
#define P2LOG2E ( 2.88539008f)   // tanh gate:     exp2(P2LOG2E*x) = e^2x

// ---------------- kernel 0: permute w_ih -> [e][u][g], fold bias + scale ----------------
__global__ __launch_bounds__(256) void k0_prep(
    const float* __restrict__ w_ih, const float* __restrict__ b_ih,
    const float* __restrict__ b_hh, float* __restrict__ wt,
    float* __restrict__ bias_t)
{
  int i = blockIdx.x * 256 + threadIdx.x;
  if (i < 64*EMB) {
    int g = i / (16*EMB);              // gate type (i,f,g,o)
    int r = i - g * (16*EMB);
    int u = r / EMB;                   // unit
    int e = r - u * EMB;               // emb col
    float s = (g == 2) ? P2LOG2E : NLOG2E;
    wt[e * 64 + u * 4 + g] = s * w_ih[i];  // coalesced read
  }
  if (i < 64) {
    int u = i >> 2, g = i & 3;
    float s = (g == 2) ? P2LOG2E : NLOG2E;
    bias_t[i] = s * (b_ih[g*16+u] + b_hh[g*16+u]);
  }
}

// ---------------- kernel 1: gather + input GEMM (LDS-broadcast weights) ----------------
// 512 blocks x 256 threads, 2 tokens/lane -> 2 blocks/CU (76.8KB LDS), 8
// waves/CU = 2 waves/SIMD for latency hiding. r9 evidence: 1 wave/SIMD (256
// blocks) exposed all DS/gather latency (~118us); r4 evidence: uniform VMEM
// weight loads cost 16KB/iter/wave through TA/L1 (~62us/CU). LDS same-address
// reads are true broadcasts (16B of bank traffic, no TA) -> FMA-issue floor.
__global__ __launch_bounds__(256, 2) void k1_pregates(
    const int* __restrict__ x, const float* __restrict__ emb,
    const float* __restrict__ wt, const float* __restrict__ bias_t,
    float* __restrict__ pre)
{
  __shared__ float4 wlds[EMB*16];       // [300][16] float4 (unit-major, gate in vec)

  const float4* __restrict__ wt4 = (const float4*)wt;
  for (int i = threadIdx.x; i < EMB*16; i += 256)   // coalesced 4KB/iter
    wlds[i] = wt4[i];

  const int q    = threadIdx.x >> 6;          // unit quarter 0..3
  const int lane = threadIdx.x & 63;
  const int t0   = blockIdx.x * 128 + lane;   // tokens t0, t0+64

  const int r0 = x[t0];
  const int r1 = x[t0 + 64];
  const float4* __restrict__ e0 = (const float4*)(emb + (size_t)r0 * EMB);
  const float4* __restrict__ e1 = (const float4*)(emb + (size_t)r1 * EMB);

  __syncthreads();

  const float4* __restrict__ wq = &wlds[q * 4];   // wave-uniform LDS base

  float4 a0[4], a1[4];
  #pragma unroll
  for (int j = 0; j < 4; ++j) { a0[j] = make_float4(0,0,0,0); a1[j] = make_float4(0,0,0,0); }

  for (int e4 = 0; e4 < EMB/4; ++e4) {   // 75 iters
    float4 v0 = e0[e4];                  // per-lane gather (16B)
    float4 v1 = e1[e4];
    #pragma unroll
    for (int ee = 0; ee < 4; ++ee) {
      const float4* wr = wq + (size_t)(e4*4 + ee) * 16;  // uniform -> LDS broadcast
      float4 w0 = wr[0], w1 = wr[1], w2 = wr[2], w3 = wr[3];
      float s0 = (ee==0) ? v0.x : (ee==1) ? v0.y : (ee==2) ? v0.z : v0.w;
      float s1 = (ee==0) ? v1.x : (ee==1) ? v1.y : (ee==2) ? v1.z : v1.w;
      a0[0].x = fmaf(s0, w0.x, a0[0].x); a0[0].y = fmaf(s0, w0.y, a0[0].y);
      a0[0].z = fmaf(s0, w0.z, a0[0].z); a0[0].w = fmaf(s0, w0.w, a0[0].w);
      a0[1].x = fmaf(s0, w1.x, a0[1].x); a0[1].y = fmaf(s0, w1.y, a0[1].y);
      a0[1].z = fmaf(s0, w1.z, a0[1].z); a0[1].w = fmaf(s0, w1.w, a0[1].w);
      a0[2].x = fmaf(s0, w2.x, a0[2].x); a0[2].y = fmaf(s0, w2.y, a0[2].y);
      a0[2].z = fmaf(s0, w2.z, a0[2].z); a0[2].w = fmaf(s0, w2.w, a0[2].w);
      a0[3].x = fmaf(s0, w3.x, a0[3].x); a0[3].y = fmaf(s0, w3.y, a0[3].y);
      a0[3].z = fmaf(s0, w3.z, a0[3].z); a0[3].w = fmaf(s0, w3.w, a0[3].w);
      a1[0].x = fmaf(s1, w0.x, a1[0].x); a1[0].y = fmaf(s1, w0.y, a1[0].y);
      a1[0].z = fmaf(s1, w0.z, a1[0].z); a1[0].w = fmaf(s1, w0.w, a1[0].w);
      a1[1].x = fmaf(s1, w1.x, a1[1].x); a1[1].y = fmaf(s1, w1.y, a1[1].y);
      a1[1].z = fmaf(s1, w1.z, a1[1].z); a1[1].w = fmaf(s1, w1.w, a1[1].w);
      a1[2].x = fmaf(s1, w2.x, a1[2].x); a1[2].y = fmaf(s1, w2.y, a1[2].y);
      a1[2].z = fmaf(s1, w2.z, a1[2].z); a1[2].w = fmaf(s1, w2.w, a1[2].w);
      a1[3].x = fmaf(s1, w3.x, a1[3].x); a1[3].y = fmaf(s1, w3.y, a1[3].y);
      a1[3].z = fmaf(s1, w3.z, a1[3].z); a1[3].w = fmaf(s1, w3.w, a1[3].w);
    }
  }

  const float4* __restrict__ bias4 = (const float4*)bias_t;  // [16] float4
  float4* __restrict__ pre4 = (float4*)pre;
  #pragma unroll
  for (int j = 0; j < 4; ++j) {
    float4 bb = bias4[q*4 + j];
    a0[j].x += bb.x; a0[j].y += bb.y; a0[j].z += bb.z; a0[j].w += bb.w;
    a1[j].x += bb.x; a1[j].y += bb.y; a1[j].z += bb.z; a1[j].w += bb.w;
    pre4[(size_t)(t0     ) * 16 + q*4 + j] = a0[j];
    pre4[(size_t)(t0 + 64) * 16 + q*4 + j] = a1[j];
  }
}

// ---------------- kernel 2: recurrence + pooling + linear ----------------
// h-broadcast via DPP row_ror:1 (pure VALU, ~2cyc) instead of the LDS round
// trip (~200cyc of the 470cyc/step chain, r9 budget). Weights are preloaded
// in rotation order by rotating the lane-id through the SAME DPP op, so the
// mapping is correct regardless of the rotation direction convention.
__device__ __forceinline__ int rot1i(int v) {
  // DPP16 ROW_ROR:1 (0x121), full row/bank masks, no bound ctrl.
  return __builtin_amdgcn_update_dpp(v, v, 0x121, 0xF, 0xF, false);
}
__device__ __forceinline__ float rot1f(float v) {
  return __int_as_float(rot1i(__float_as_int(v)));
}

// 32 blocks x 64 threads: one wave = 4 batches x 16 units (DPP rows = batches).
__global__ __launch_bounds__(64, 1) void k2_lstm(
    const int* __restrict__ lengths,
    const float* __restrict__ w_hh,
    const float* __restrict__ w_lin,
    const float* __restrict__ b_lin,
    const float* __restrict__ pre,
    float* __restrict__ out)
{
  const int tid = threadIdx.x;
  const int u  = tid & 15;        // hidden unit
  const int bl = tid >> 4;        // local batch (0..3)
  const int b  = blockIdx.x * 4 + bl;

  // Preload w_hh rows for unit u in ROTATION order, pre-scaled for exp2.
  // kidx follows the exact permutation the in-loop h-rotation applies.
  const float* __restrict__ Wi = w_hh + (0*HID + u) * HID;
  const float* __restrict__ Wf = w_hh + (1*HID + u) * HID;
  const float* __restrict__ Wg = w_hh + (2*HID + u) * HID;
  const float* __restrict__ Wo = w_hh + (3*HID + u) * HID;
  float wi[16], wf[16], wg[16], wo[16];
  int kidx = u;
  #pragma unroll
  for (int r = 0; r < 16; ++r) {
    wi[r] = NLOG2E  * Wi[kidx];
    wf[r] = NLOG2E  * Wf[kidx];
    wg[r] = P2LOG2E * Wg[kidx];
    wo[r] = NLOG2E  * Wo[kidx];
    kidx = rot1i(kidx);
  }

  int L = lengths[b];
  L = (L < 1) ? 1 : (L > SEQ ? SEQ : L);

  // wave-level max length (4 batches in this wave) for early exit
  int Lw = L;
  Lw = max(Lw, __shfl_xor(Lw, 16, 64));
  Lw = max(Lw, __shfl_xor(Lw, 32, 64));

  const float4* __restrict__ pp = (const float4*)pre + (size_t)b * SEQ * 16 + u;

  float h = 0.f, c = 0.f;
  float s_sum = 0.f, s_max = -3.4e38f, s_last = 0.f;

  // software pipeline: 8-deep prefetch
  float4 buf[8];
  #pragma unroll
  for (int p = 0; p < 8; ++p) buf[p] = pp[(size_t)p * 16];

  for (int g = 0; g < SEQ/8; ++g) {
    if (g * 8 >= Lw) break;    // wave-uniform early exit
    #pragma unroll
    for (int p = 0; p < 8; ++p) {
      float4 cur = buf[p];
      buf[p] = pp[((size_t)(g+1)*8 + p) * 16];   // prefetch (ws slack covers overrun)
      const int s = g*8 + p;

      // rotation matvec: 15 DPP rotations + 64 scalar FMAs, all VALU
      float hr = h;
      float ai = fmaf(wi[0], hr, cur.x);
      float af = fmaf(wf[0], hr, cur.y);
      float ag = fmaf(wg[0], hr, cur.z);
      float ao = fmaf(wo[0], hr, cur.w);
      #pragma unroll
      for (int r = 1; r < 16; ++r) {
        hr = rot1f(hr);
        ai = fmaf(wi[r], hr, ai);
        af = fmaf(wf[r], hr, af);
        ag = fmaf(wg[r], hr, ag);
        ao = fmaf(wo[r], hr, ao);
      }

      // activations (accs pre-scaled: exp2 only)
      float i_ = __builtin_amdgcn_rcpf(1.f + __builtin_amdgcn_exp2f(ai));
      float f_ = __builtin_amdgcn_rcpf(1.f + __builtin_amdgcn_exp2f(af));
      float g_ = fmaf(-2.f, __builtin_amdgcn_rcpf(1.f + __builtin_amdgcn_exp2f(ag)), 1.f);
      float o_ = __builtin_amdgcn_rcpf(1.f + __builtin_amdgcn_exp2f(ao));
      c = fmaf(f_, c, i_ * g_);
      float tc = fmaf(-2.f, __builtin_amdgcn_rcpf(1.f + __builtin_amdgcn_exp2f(P2LOG2E * c)), 1.f);
      h = o_ * tc;

      bool act = (s < L);
      s_sum  += act ? h : 0.f;
      s_max   = act ? fmaxf(s_max, h) : s_max;
      s_last  = (s == L - 1) ? h : s_last;
    }
  }

  // stage rep = [last(16) | sum(16) | max(16)] per batch, then 48->5 linear
  __shared__ float rep[4][48];
  rep[bl][u]      = s_last;
  rep[bl][16 + u] = s_sum;
  rep[bl][32 + u] = s_max;
  __syncthreads();

  if (tid < 4 * OUTD) {
    int bo = tid / OUTD;       // local batch
    int o  = tid % OUTD;       // output idx
    float acc = b_lin[o];
    #pragma unroll
    for (int k = 0; k < 48; ++k)
      acc = fmaf(rep[bo][k], w_lin[o * 48 + k], acc);
    out[(blockIdx.x * 4 + bo) * OUTD + o] = acc;
  }
}

// ---------------- launcher ----------------
extern "C" void kernel_launch(void* const* d_in, const int* in_sizes, int n_in,
                              void* d_out, int out_size, void* d_ws, size_t ws_size,
                              hipStream_t stream)
{
  const int*   x      = (const int*)d_in[0];
  const int*   lens   = (const int*)d_in[1];
  const float* emb    = (const float*)d_in[2];
  const float* w_ih   = (const float*)d_in[3];
  const float* w_hh   = (const float*)d_in[4];
  const float* b_ih   = (const float*)d_in[5];
  const float* b_hh   = (const float*)d_in[6];
  const float* w_lin  = (const float*)d_in[7];
  const float* b_lin  = (const float*)d_in[8];
  float* out = (float*)d_out;

  float* ws     = (float*)d_ws;
  float* wt     = ws + WT_OFF;
  float* bias_t = ws + BIAS_OFF;
  float* pre    = ws + PRE_OFF;

  hipLaunchKernelGGL(k0_prep,     dim3(75),  dim3(256), 0, stream, w_ih, b_ih, b_hh, wt, bias_t);
  hipLaunchKernelGGL(k1_pregates, dim3(512), dim3(256), 0, stream, x, emb, wt, bias_t, pre);
  hipLaunchKernelGGL(k2_lstm,     dim3(32),  dim3(64),  0, stream, lens, w_hh, w_lin, b_lin, pre, out);
}